// Round 1
// baseline (420.293 us; speedup 1.0000x reference)
//
#include <hip/hip_runtime.h>
#include <hip/hip_bf16.h>

// Problem: B=32, S=1, DIM=4096, NH=32, NKV=8, HD=128, MAXLEN=4096, START_POS=4095.
// All fp32. Memory-bound: KV cache 1 GB + weights 160 MB -> ~188 us roofline @6.3TB/s.

#define DIM   4096
#define NKV   8
#define NREP  4
#define HD    128
#define MAXLEN 4096

// ---------------------------------------------------------------------------
// GEMV-batch core: C[n*M + m] = sum_k W[m*4096+k] * X[n*4096+k], n in [0,32)
// Block: 512 threads = 8 waves. Block covers 16 rows (m0..m0+15).
// Each wave owns K-slice [wave*512, wave*512+512) with private LDS staging
// (no intra-loop barriers). Thread: 1 row (lane&15) x 8 cols (lane>>4)*8.
// ---------------------------------------------------------------------------
__device__ __forceinline__ void gemv_core(const float* __restrict__ W,
                                          const float* __restrict__ X,
                                          float* __restrict__ C,
                                          const int M, const int m0)
{
    constexpr int K = 4096;
    const int tid  = threadIdx.x;
    const int wave = tid >> 6;      // 0..7
    const int lane = tid & 63;
    const int r    = lane & 15;     // row within 16-row tile
    const int cg   = lane >> 4;     // col group 0..3 -> cols cg*8..cg*8+7
    const int rr0  = lane >> 3;     // 0..7 (staging row/batch base)
    const int c40  = lane & 7;      // 0..7 (staging float4 column)

    __shared__ union {
        struct {
            float Wt[8][32][17];    // [wave][kk][row]  (pad 17: conflict-free)
            float Xl[8][32][36];    // [wave][kk][b]    (pad 36: 16B-aligned rows)
        } s;
        float red[8][16][32];       // cross-wave reduction (reused after loop)
    } u;

    float acc[8];
#pragma unroll
    for (int j = 0; j < 8; ++j) acc[j] = 0.f;

    const int kbase = wave * 512;
    for (int c = 0; c < 16; ++c) {
        const int k0 = kbase + c * 32;
        // stage W tile: 16 rows x 32 k  (coalesced float4, scalar LDS scatter)
#pragma unroll
        for (int i = 0; i < 2; ++i) {
            const int rr = rr0 + 8 * i;
            const float4 wv = *(const float4*)(W + (size_t)(m0 + rr) * K + k0 + c40 * 4);
            u.s.Wt[wave][c40 * 4 + 0][rr] = wv.x;
            u.s.Wt[wave][c40 * 4 + 1][rr] = wv.y;
            u.s.Wt[wave][c40 * 4 + 2][rr] = wv.z;
            u.s.Wt[wave][c40 * 4 + 3][rr] = wv.w;
        }
        // stage X tile: 32 batches x 32 k (L2-resident, 512 KB total)
#pragma unroll
        for (int i = 0; i < 4; ++i) {
            const int bb = rr0 + 8 * i;
            const float4 xv = *(const float4*)(X + (size_t)bb * K + k0 + c40 * 4);
            u.s.Xl[wave][c40 * 4 + 0][bb] = xv.x;
            u.s.Xl[wave][c40 * 4 + 1][bb] = xv.y;
            u.s.Xl[wave][c40 * 4 + 2][bb] = xv.z;
            u.s.Xl[wave][c40 * 4 + 3][bb] = xv.w;
        }
        // same-wave LDS dep: compiler inserts lgkmcnt; DS ops are in-order per wave
#pragma unroll
        for (int kk = 0; kk < 32; ++kk) {
            const float wv = u.s.Wt[wave][kk][r];
            const float4 xa = *(const float4*)&u.s.Xl[wave][kk][cg * 8];
            const float4 xb = *(const float4*)&u.s.Xl[wave][kk][cg * 8 + 4];
            acc[0] = fmaf(wv, xa.x, acc[0]);
            acc[1] = fmaf(wv, xa.y, acc[1]);
            acc[2] = fmaf(wv, xa.z, acc[2]);
            acc[3] = fmaf(wv, xa.w, acc[3]);
            acc[4] = fmaf(wv, xb.x, acc[4]);
            acc[5] = fmaf(wv, xb.y, acc[5]);
            acc[6] = fmaf(wv, xb.z, acc[6]);
            acc[7] = fmaf(wv, xb.w, acc[7]);
        }
    }

    __syncthreads();   // protect union aliasing (all waves done with Wt/Xl)
#pragma unroll
    for (int j = 0; j < 8; ++j) u.red[wave][r][cg * 8 + j] = acc[j];
    __syncthreads();

    // 512 threads -> 16 rows x 32 cols, sum the 8 K-slices
    {
        const int r2 = tid >> 5;   // 0..15
        const int n  = tid & 31;   // batch
        float ssum = 0.f;
#pragma unroll
        for (int w = 0; w < 8; ++w) ssum += u.red[w][r2][n];
        C[(size_t)n * M + m0 + r2] = ssum;
    }
}

// Fused QKV projection: grid = 256 (wq) + 64 (wk) + 64 (wv) blocks
__global__ __launch_bounds__(512) void qkv_kernel(
    const float* __restrict__ wq, const float* __restrict__ wk,
    const float* __restrict__ wv, const float* __restrict__ x,
    float* __restrict__ q_ws, float* __restrict__ k_ws, float* __restrict__ v_ws)
{
    const int bx = blockIdx.x;
    if (bx < 256)      gemv_core(wq, x, q_ws, 4096, bx * 16);
    else if (bx < 320) gemv_core(wk, x, k_ws, 1024, (bx - 256) * 16);
    else               gemv_core(wv, x, v_ws, 1024, (bx - 320) * 16);
}

// Output projection: grid = 256 blocks
__global__ __launch_bounds__(512) void out_kernel(
    const float* __restrict__ wo, const float* __restrict__ attn,
    float* __restrict__ out)
{
    gemv_core(wo, attn, out, 4096, blockIdx.x * 16);
}

// ---------------------------------------------------------------------------
// Attention: one block per (b, g). 512 threads = 8 waves; each half-wave (32
// lanes) processes one cache row per step (float4/lane, 512 B coalesced).
// Online softmax per half-wave; flash-combine 16 partials at the end.
// RoPE applied to q and to the new-token k in-register; l==4095 reads the new
// roped k/v from LDS (inputs never mutated).
// ---------------------------------------------------------------------------
__global__ __launch_bounds__(512) void attn_kernel(
    const float* __restrict__ qws, const float* __restrict__ kws,
    const float* __restrict__ vws, const float* __restrict__ freqs,
    const float* __restrict__ cache_k, const float* __restrict__ cache_v,
    float* __restrict__ outws)
{
    const int tid  = threadIdx.x;
    const int wave = tid >> 6;
    const int lane = tid & 63;
    const int half = (lane >> 5) & 1;
    const int ln   = lane & 31;        // d-slice index: d = 4*ln .. 4*ln+3
    const int hw   = wave * 2 + half;  // 0..15
    const int bx = blockIdx.x;
    const int b = bx >> 3, g = bx & 7;

    __shared__ float4 kn[32], vn[32];          // roped new k, new v
    __shared__ float  pm[16][4], ps[16][4];    // per-halfwave max / sumexp
    __shared__ float4 pacc[16][4][32];         // per-halfwave weighted V acc

    // freqs layout (HD/2, 2) interleaved (c,s): float4 @4ln = {c0,s0,c1,s1}
    const float4 fr = *(const float4*)(freqs + 4 * ln);
    const float scale = 0.08838834764831845f;  // 1/sqrt(128)

    float4 q4[4];
#pragma unroll
    for (int h = 0; h < 4; ++h) {
        const float4 t = *(const float4*)(qws + (size_t)b * 4096 + (size_t)(g * 4 + h) * 128 + 4 * ln);
        q4[h].x = (t.x * fr.x - t.y * fr.y) * scale;
        q4[h].y = (t.x * fr.y + t.y * fr.x) * scale;
        q4[h].z = (t.z * fr.z - t.w * fr.w) * scale;
        q4[h].w = (t.z * fr.w + t.w * fr.z) * scale;
    }
    if (tid < 32) {
        const float4 f2 = *(const float4*)(freqs + 4 * tid);
        const float4 t  = *(const float4*)(kws + (size_t)b * 1024 + g * 128 + 4 * tid);
        float4 kk_;
        kk_.x = t.x * f2.x - t.y * f2.y;
        kk_.y = t.x * f2.y + t.y * f2.x;
        kk_.z = t.z * f2.z - t.w * f2.w;
        kk_.w = t.z * f2.w + t.w * f2.z;
        kn[tid] = kk_;
        vn[tid] = *(const float4*)(vws + (size_t)b * 1024 + g * 128 + 4 * tid);
    }
    __syncthreads();

    const float* kb = cache_k + (size_t)b * MAXLEN * 1024 + g * 128 + 4 * ln;
    const float* vb = cache_v + (size_t)b * MAXLEN * 1024 + g * 128 + 4 * ln;

    float  m[4]  = {-1e30f, -1e30f, -1e30f, -1e30f};
    float  ss[4] = {0.f, 0.f, 0.f, 0.f};
    float4 acc[4];
#pragma unroll
    for (int h = 0; h < 4; ++h) { acc[h].x = acc[h].y = acc[h].z = acc[h].w = 0.f; }

    auto proc = [&](const float4 kv, const float4 vv) {
        float s[4];
#pragma unroll
        for (int h = 0; h < 4; ++h) {
            float t = fmaf(q4[h].x, kv.x, fmaf(q4[h].y, kv.y, fmaf(q4[h].z, kv.z, q4[h].w * kv.w)));
#pragma unroll
            for (int mask = 16; mask >= 1; mask >>= 1)
                t += __shfl_xor(t, mask, 64);   // masks<=16 stay within the half
            s[h] = t;
        }
#pragma unroll
        for (int h = 0; h < 4; ++h) {
            const float nm   = fmaxf(m[h], s[h]);
            const float corr = __expf(m[h] - nm);
            const float pe   = __expf(s[h] - nm);
            ss[h]    = fmaf(ss[h], corr, pe);
            acc[h].x = fmaf(acc[h].x, corr, pe * vv.x);
            acc[h].y = fmaf(acc[h].y, corr, pe * vv.y);
            acc[h].z = fmaf(acc[h].z, corr, pe * vv.z);
            acc[h].w = fmaf(acc[h].w, corr, pe * vv.w);
            m[h] = nm;
        }
    };

    // pairs p: half-wave handles row l = 2p+half; wave covers p = wave (+8) mod 16
    for (int p = wave; p < 2048; p += 16) {
        const int l0 = 2 * p + half;
        const int l1 = l0 + 16;
        const float4 k0 = *(const float4*)(kb + (size_t)l0 * 1024);
        const float4 v0 = *(const float4*)(vb + (size_t)l0 * 1024);
        float4 k1, v1;
        if (l1 == 4095) { k1 = kn[ln]; v1 = vn[ln]; }   // new token (roped)
        else {
            k1 = *(const float4*)(kb + (size_t)l1 * 1024);
            v1 = *(const float4*)(vb + (size_t)l1 * 1024);
        }
        proc(k0, v0);
        proc(k1, v1);
    }

    if (ln == 0) {
#pragma unroll
        for (int h = 0; h < 4; ++h) { pm[hw][h] = m[h]; ps[hw][h] = ss[h]; }
    }
#pragma unroll
    for (int h = 0; h < 4; ++h) pacc[hw][h][ln] = acc[h];
    __syncthreads();

    // combine 16 partials: 128 threads -> (head h, d-slice j)
    if (tid < 128) {
        const int h = tid >> 5, j = tid & 31;
        float M = -1e30f;
#pragma unroll
        for (int i = 0; i < 16; ++i) M = fmaxf(M, pm[i][h]);
        float S = 0.f, ox = 0.f, oy = 0.f, oz = 0.f, ow = 0.f;
#pragma unroll
        for (int i = 0; i < 16; ++i) {
            const float wgt = __expf(pm[i][h] - M);
            S = fmaf(ps[i][h], wgt, S);
            const float4 a = pacc[i][h][j];
            ox = fmaf(a.x, wgt, ox);
            oy = fmaf(a.y, wgt, oy);
            oz = fmaf(a.z, wgt, oz);
            ow = fmaf(a.w, wgt, ow);
        }
        const float inv = 1.f / S;
        float4 o;
        o.x = ox * inv; o.y = oy * inv; o.z = oz * inv; o.w = ow * inv;
        *(float4*)(outws + (size_t)b * 4096 + (size_t)(g * 4 + h) * 128 + 4 * j) = o;
    }
}

extern "C" void kernel_launch(void* const* d_in, const int* in_sizes, int n_in,
                              void* d_out, int out_size, void* d_ws, size_t ws_size,
                              hipStream_t stream)
{
    const float* x       = (const float*)d_in[0];
    const float* freqs   = (const float*)d_in[1];
    const float* cache_k = (const float*)d_in[2];
    const float* cache_v = (const float*)d_in[3];
    const float* wq      = (const float*)d_in[4];
    const float* wk      = (const float*)d_in[5];
    const float* wv      = (const float*)d_in[6];
    const float* wo      = (const float*)d_in[7];
    // d_in[8] = start_pos (always 4095, hardcoded)

    float* out  = (float*)d_out;
    float* ws   = (float*)d_ws;
    float* q_ws = ws;                       // 32*4096
    float* k_ws = ws + 131072;              // 32*1024
    float* v_ws = ws + 131072 + 32768;      // 32*1024
    float* a_ws = ws + 131072 + 65536;      // 32*4096

    qkv_kernel<<<384, 512, 0, stream>>>(wq, wk, wv, x, q_ws, k_ws, v_ws);
    attn_kernel<<<256, 512, 0, stream>>>(q_ws, k_ws, v_ws, freqs, cache_k, cache_v, a_ws);
    out_kernel<<<256, 512, 0, stream>>>(wo, a_ws, out);
}